// Round 5
// baseline (421.702 us; speedup 1.0000x reference)
//
#include <hip/hip_runtime.h>

// Problem constants (from reference): N=4096 agents, TOP_K=12, OBS_RADIUS=1.0
#define NN    4096
#define TOPK  12
#define NP    (NN * TOPK)        // 49152 pairs
// d_out layout (float32): out[0..NP), mask[NP..2NP), indices[2NP..2NP+2NP) as (row, j)
#define OFF_MASK (NP)
#define OFF_IDX  (2 * NP)

#define GROUPS 256               // 19 blocks per group: 16 topk producers + 3 MLP consumers
#define GRID   (GROUPS * 19)     // 4864 blocks; rows 16/group, pairs 192/group
#define SPIN   10000             // poll cap; timeout -> self-compute fallback (no deadlock)

// Ascending 64-lane bitonic sort on packed u64 keys (verified in prior kernels).
__device__ __forceinline__ unsigned long long bitonic64(unsigned long long key, int lane) {
    #pragma unroll
    for (int k = 2; k <= 64; k <<= 1) {
        #pragma unroll
        for (int jj = k >> 1; jj >= 1; jj >>= 1) {
            unsigned long long ok = __shfl_xor(key, jj, 64);
            bool keepMin = ((lane & k) == 0) == ((lane & jj) == 0);
            unsigned long long mn = (ok < key) ? ok : key;
            unsigned long long mx = (ok < key) ? key : ok;
            key = keepMin ? mn : mx;
        }
    }
    return key;
}

// ---------------------------------------------------------------------------
// Verified threshold-select top-12 for ONE row, 256 threads. Barrier-uniform:
// BOTH paths (fast compact / pathological-ties 12-pop fallback) execute
// exactly 4 __syncthreads, so it is callable from divergent block roles.
// Publishes results twice: out[] (harness layout) and wsf[] packed atomics
// ((j<<2)|(mask<<1)|1, nonzero by construction) for the pipeline consumers.
// Semantics identical to the 404us-verified kernel (same keys, same sorts,
// same tie-breaks, same fallback).
// ---------------------------------------------------------------------------
__device__ __forceinline__ void topk_one_row(
        const float* __restrict__ x, float* __restrict__ out,
        int* __restrict__ wsf, int i, int t,
        unsigned long long* cand, unsigned long long* wtop,
        float* Tsh, int* cnt) {
    const int lane = t & 63;
    const int w    = t >> 6;
    const float4* x4 = (const float4*)x + (size_t)i * NN;

    float s[16];
    #pragma unroll
    for (int k = 0; k < 16; ++k) {
        float4 v = x4[(k << 8) + t];
        s[k] = v.x * v.x + v.y * v.y;
    }
    float bs = s[0]; int bj = t;
    #pragma unroll
    for (int k = 1; k < 16; ++k) {
        int j = (k << 8) + t;
        if (s[k] < bs) { bs = s[k]; bj = j; }
    }
    unsigned long long bk =
        ((unsigned long long)__float_as_uint(bs) << 32) | (unsigned)bj;

    // Phase A: per-wave sort of lane-minima; keep top-12.
    {
        unsigned long long key = bitonic64(bk, lane);
        if (lane < TOPK) wtop[w * TOPK + lane] = key;
    }
    __syncthreads();                                        // (1)

    // Phase B: exact 12th-smallest minimum T.
    if (w == 0) {
        unsigned long long k2 = (lane < 4 * TOPK) ? wtop[lane] : ~0ULL;
        k2 = bitonic64(k2, lane);
        if (lane == TOPK - 1) *Tsh = __uint_as_float((unsigned)(k2 >> 32));
    }
    __syncthreads();                                        // (2)
    const float T = *Tsh;

    // Phase C: filter + wave prefix.
    int c = 0;
    #pragma unroll
    for (int k = 0; k < 16; ++k) c += (s[k] <= T) ? 1 : 0;
    int pfx = c;
    #pragma unroll
    for (int off = 1; off < 64; off <<= 1) {
        int o = __shfl_up(pfx, off, 64);
        if (lane >= off) pfx += o;
    }
    if (lane == 63) cnt[w] = pfx;
    __syncthreads();                                        // (3)

    const int total = cnt[0] + cnt[1] + cnt[2] + cnt[3];    // block-uniform

    if (total <= 64) {
        int base = 0;
        for (int ww = 0; ww < w; ++ww) base += cnt[ww];
        int o = base + (pfx - c);
        #pragma unroll
        for (int k = 0; k < 16; ++k) {
            if (s[k] <= T)
                cand[o++] = ((unsigned long long)__float_as_uint(s[k]) << 32)
                            | (unsigned)((k << 8) + t);
        }
    } else {
        // Fallback (pathological ties only): verified wave-local 12-pop.
        unsigned long long mykey = ~0ULL;
        for (int it = 0; it < TOPK; ++it) {
            unsigned long long vk = bk;
            #pragma unroll
            for (int off = 1; off < 64; off <<= 1) {
                unsigned long long ok = __shfl_xor(vk, off, 64);
                vk = (ok < vk) ? ok : vk;
            }
            if (lane == it) mykey = vk;
            int wj = (int)(vk & 0xffffffffULL);
            if ((wj & 63) == lane) {
                int kk = wj >> 8;
                #pragma unroll
                for (int k = 0; k < 16; ++k)
                    if (k == kk) s[k] = 3.0e38f;
                float nbs = s[0]; int nbj = t;
                #pragma unroll
                for (int k = 1; k < 16; ++k) {
                    int j = (k << 8) + t;
                    if (s[k] < nbs) { nbs = s[k]; nbj = j; }
                }
                bk = ((unsigned long long)__float_as_uint(nbs) << 32) | (unsigned)nbj;
            }
        }
        if (lane < TOPK) cand[w * TOPK + lane] = mykey;
    }
    __syncthreads();                                        // (4)

    const int n = (total <= 64) ? total : (4 * TOPK);
    if (w == 0) {
        unsigned long long k3 = (lane < n) ? cand[lane] : ~0ULL;
        k3 = bitonic64(k3, lane);
        if (lane < TOPK) {
            int   j  = (int)(k3 & 0xffffffffULL);
            float ss = __uint_as_float((unsigned)(k3 >> 32));
            float d  = sqrtf(ss + 2.0e-4f);      // sqrt(sum(x[:2]^2 + 1e-4))
            int   mb = (d <= 1.0f) ? 1 : 0;
            int p = i * TOPK + lane;
            out[OFF_MASK + p]        = (float)mb;
            out[OFF_IDX + 2 * p]     = (float)i;
            out[OFF_IDX + 2 * p + 1] = (float)j;
            atomicExch(&wsf[i * TOPK + lane], (j << 2) | (mb << 1) | 1);
        }
    }
}

// ---------------------------------------------------------------------------
// Pipelined kernel. Group G (19 blocks): roles 0..15 = producers for rows
// 16G..16G+15; roles 16..18 = consumers for pair-blocks 3G..3G+2 (64 pairs
// each; consumer c needs exactly rows 16G+⌊64c/12⌋..+5 — all inside group G,
// all dispatched BEFORE it). Consumers spin on the packed atomics (value IS
// the data -> no separate data fence needed), with self-compute fallback on
// timeout so correctness never depends on dispatch order (G16).
// MLP internals = verified mlp_block with 4 waves x 2 sequential chunks
// (identical scalar-weight addressing, identical summation order).
// LDS 51.8 KB -> 3 blocks/CU, 12 waves/CU (streaming needs ~10KB in flight;
// 12 waves supply ~190KB).
// ---------------------------------------------------------------------------
__global__ __launch_bounds__(256, 3) void cbf_pipe(
        const float* __restrict__ x, const float* __restrict__ rp,
        const float* __restrict__ W1, const float* __restrict__ b1,
        const float* __restrict__ W2, const float* __restrict__ b2,
        const float* __restrict__ W3, const float* __restrict__ b3,
        const float* __restrict__ W4, const float* __restrict__ b4,
        float* __restrict__ out, int* __restrict__ wsf) {
    __shared__ __align__(16) float h1s[64 * 64];   // 16 KB  [neuron][pair]
    __shared__ float h2s[128 * 64];                // 32 KB  [neuron][pair]
    __shared__ float p4s[8 * 64];                  //  2 KB  [chunk][pair]
    __shared__ int   jmj[6 * TOPK];                // per-consumer j table
    __shared__ float jmm[6 * TOPK];                // per-consumer mask table
    __shared__ int   nrdy[6];

    // top-k scratch unioned into h1s (dead before MLP phase 1 writes it)
    unsigned long long* cand = (unsigned long long*)h1s;      // 512 B
    unsigned long long* wtop = cand + 64;                     // 384 B
    float* Tsh = (float*)(wtop + 4 * TOPK);
    int*   cnt = (int*)(Tsh + 1);

    const int g    = blockIdx.x;
    const int t    = threadIdx.x;
    const int G    = g / 19;
    const int role = g % 19;

    if (role < 16) {
        topk_one_row(x, out, wsf, G * 16 + role, t, cand, wtop, Tsh, cnt);
        return;
    }

    // ---------------- consumer: 64 pairs = rows r0..r0+5 -------------------
    const int mb = G * 3 + (role - 16);            // pair-block 0..767
    const int r0 = (mb * 64) / TOPK;               // spans exactly 6 rows

    if (t < 6) nrdy[t] = 0;
    __syncthreads();
    if (t < 72) {
        int* f = &wsf[(r0 + t / TOPK) * TOPK + (t % TOPK)];
        int v = 0;
        for (int it = 0; it < SPIN; ++it) {
            v = atomicAdd(f, 0);
            if (v) break;
            __builtin_amdgcn_s_sleep(4);
        }
        if (!v) nrdy[t / TOPK] = 1;                // benign same-value race
    }
    __syncthreads();
    for (int r = 0; r < 6; ++r) {                  // uniform branch (LDS)
        if (nrdy[r]) {
            topk_one_row(x, out, wsf, r0 + r, t, cand, wtop, Tsh, cnt);
            __syncthreads();
        }
    }
    if (t < 72) {                                  // now guaranteed nonzero
        int v = atomicAdd(&wsf[(r0 + t / TOPK) * TOPK + (t % TOPK)], 0);
        jmj[t] = v >> 2;
        jmm[t] = ((v >> 1) & 1) ? 1.0f : 0.0f;
    }
    __syncthreads();

    // ---------------- MLP: 64 pairs, 4 waves x 2 chunks --------------------
    const int pl = t & 63;                         // pair lane
    const int wv = t >> 6;                         // wave 0..3
    const int p  = mb * 64 + pl;
    const int ip = p / TOPK;
    const int li = ip - r0;
    const int kk = p % TOPK;
    const int jj = jmj[li * TOPK + kk];

    const float4 v = ((const float4*)x)[(size_t)ip * NN + jj];
    const float d  = sqrtf(v.x * v.x + v.y * v.y + 2.0e-4f);
    float xin[6];
    xin[0] = v.x; xin[1] = v.y; xin[2] = v.z; xin[3] = v.w;
    xin[4] = (ip == jj) ? 1.0f : 0.0f;
    xin[5] = d - rp[0];

    // Phase 1: h1 neurons, chunks {2wv, 2wv+1}   (weights via s_load)
    #pragma unroll
    for (int half = 0; half < 2; ++half) {
        const int ch = __builtin_amdgcn_readfirstlane(wv * 2 + half);
        #pragma unroll
        for (int q = 0; q < 8; ++q) {
            int m = ch * 8 + q;
            float a = b1[m];
            #pragma unroll
            for (int c2 = 0; c2 < 6; ++c2) a += W1[m * 6 + c2] * xin[c2];
            h1s[m * 64 + pl] = fmaxf(a, 0.0f);
        }
    }
    __syncthreads();

    // Phase 2: h2 neurons, k streamed in parts of 16 (order == verified K2)
    #pragma unroll
    for (int half = 0; half < 2; ++half) {
        const int ch = __builtin_amdgcn_readfirstlane(wv * 2 + half);
        float acc[16];
        #pragma unroll
        for (int q = 0; q < 16; ++q) acc[q] = b2[ch * 16 + q];
        for (int part = 0; part < 4; ++part) {
            float h1r[16];
            #pragma unroll
            for (int k = 0; k < 16; ++k) h1r[k] = h1s[(part * 16 + k) * 64 + pl];
            #pragma unroll
            for (int q = 0; q < 16; ++q) {
                const float* w2 = W2 + (ch * 16 + q) * 64 + part * 16;
                #pragma unroll
                for (int k = 0; k < 16; ++k) acc[q] += w2[k] * h1r[k];
            }
        }
        #pragma unroll
        for (int q = 0; q < 16; ++q) h2s[(ch * 16 + q) * 64 + pl] = fmaxf(acc[q], 0.0f);
    }
    __syncthreads();

    // Phase 3 + layer-4 partials
    #pragma unroll
    for (int half = 0; half < 2; ++half) {
        const int ch = __builtin_amdgcn_readfirstlane(wv * 2 + half);
        float h3[8];
        #pragma unroll
        for (int q = 0; q < 8; ++q) h3[q] = b3[ch * 8 + q];
        for (int part = 0; part < 8; ++part) {
            float h2r[16];
            #pragma unroll
            for (int k = 0; k < 16; ++k) h2r[k] = h2s[(part * 16 + k) * 64 + pl];
            #pragma unroll
            for (int q = 0; q < 8; ++q) {
                const float* w3 = W3 + (ch * 8 + q) * 128 + part * 16;
                #pragma unroll
                for (int k = 0; k < 16; ++k) h3[q] += w3[k] * h2r[k];
            }
        }
        float partial = 0.0f;
        #pragma unroll
        for (int q = 0; q < 8; ++q) partial += W4[ch * 8 + q] * fmaxf(h3[q], 0.0f);
        p4s[ch * 64 + pl] = partial;
    }
    __syncthreads();

    // Phase 4: reduce 8 chunk-partials per pair (ascending chunk order)
    if (t < 64) {
        float s2 = b4[0];
        #pragma unroll
        for (int c2 = 0; c2 < 8; ++c2) s2 += p4s[c2 * 64 + t];
        int pp  = mb * 64 + t;
        int ip2 = pp / TOPK;
        out[pp] = s2 * jmm[(ip2 - r0) * TOPK + (pp % TOPK)];
    }
}

// ---------------------------------------------------------------------------
extern "C" void kernel_launch(void* const* d_in, const int* in_sizes, int n_in,
                              void* d_out, int out_size, void* d_ws, size_t ws_size,
                              hipStream_t stream) {
    const float* x  = (const float*)d_in[0];
    const float* rp = (const float*)d_in[1];
    const float* W1 = (const float*)d_in[2];
    const float* b1 = (const float*)d_in[3];
    const float* W2 = (const float*)d_in[4];
    const float* b2 = (const float*)d_in[5];
    const float* W3 = (const float*)d_in[6];
    const float* b3 = (const float*)d_in[7];
    const float* W4 = (const float*)d_in[8];
    const float* b4 = (const float*)d_in[9];
    float* out = (float*)d_out;
    int*   wsf = (int*)d_ws;

    hipMemsetAsync(wsf, 0, NP * sizeof(int), stream);   // stream op: graph-safe
    cbf_pipe<<<GRID, 256, 0, stream>>>(x, rp, W1, b1, W2, b2, W3, b3, W4, b4,
                                       out, wsf);
}

// Round 6
// 405.181 us; speedup vs baseline: 1.0408x; 1.0408x over previous
//
#include <hip/hip_runtime.h>

// Problem constants (from reference): N=4096 agents, TOP_K=12, OBS_RADIUS=1.0
#define NN    4096
#define TOPK  12
#define NP    (NN * TOPK)        // 49152 pairs
// d_out layout (float32): out[0..NP), mask[NP..2NP), indices[2NP..2NP+2NP) as (row, j)
#define OFF_MASK (NP)
#define OFF_IDX  (2 * NP)

// Ascending 64-lane bitonic sort on packed u64 keys (verified in prior kernel).
__device__ __forceinline__ unsigned long long bitonic64(unsigned long long key, int lane) {
    #pragma unroll
    for (int k = 2; k <= 64; k <<= 1) {
        #pragma unroll
        for (int jj = k >> 1; jj >= 1; jj >>= 1) {
            unsigned long long ok = __shfl_xor(key, jj, 64);
            bool keepMin = ((lane & k) == 0) == ((lane & jj) == 0);
            unsigned long long mn = (ok < key) ? ok : key;
            unsigned long long mx = (ok < key) ? key : ok;
            key = keepMin ? mn : mx;
        }
    }
    return key;
}

// ---------------------------------------------------------------------------
// K1: per-row top-12 smallest squared 2D distance. One block (256 thr) per row.
// Threshold-select structure (verified):
//   T = 12th-smallest of the 256 per-thread minima is a provable upper bound
//   on the true 12th-smallest of the row. Filter the 16 register-resident
//   values per thread against T, prefix-compact survivors (expected ~12-14,
//   cap 64) into LDS, one final 64-lane bitonic sort, write.
//   Key = (f32 bits of s)<<32 | j — u64 order == (s, j) lexicographic.
//   Fallback (>64 survivors, pathological ties only): verified wave-local
//   12-pop path on the untouched s[]/bk registers.
// SESSION NOTES (rounds 3/5 post-mortems): do NOT fuse or pipeline the MLP
// with this kernel.
//  - Per-row fusion breaks the MLP's scalar-weight addressing (12 pairs
//    can't feed a wave; per-lane weight loads thrash L1): 459us vs 404us.
//  - Producer/consumer single-launch pipeline forces the MLP's 50KB LDS
//    allocation onto the streaming blocks, halving K1 occupancy: 421us.
// K1 runs at ~89% of its 268MB stream floor; K2 at ~3.3x vector-FMA floor
// (LDS/barrier bound); ~320us of the timed region is harness poison fills
// at 83-85% HBM peak. 404.6us == 99.6% of this structure's floor.
// ---------------------------------------------------------------------------
__global__ __launch_bounds__(256, 6) void topk_rows(const float* __restrict__ x,
                                                    float* __restrict__ out) {
    const int i    = blockIdx.x;   // row
    const int t    = threadIdx.x;  // 0..255
    const int lane = t & 63;
    const int w    = t >> 6;       // wave 0..3
    const float4* x4 = (const float4*)x + (size_t)i * NN;

    // Stage: j = k*256 + t  (coalesced float4 loads)
    float s[16];
    #pragma unroll
    for (int k = 0; k < 16; ++k) {
        float4 v = x4[(k << 8) + t];
        s[k] = v.x * v.x + v.y * v.y;
    }

    // Per-thread min as packed key (ascending j scan, strict < => lowest j on tie)
    float bs = s[0]; int bj = t;
    #pragma unroll
    for (int k = 1; k < 16; ++k) {
        int j = (k << 8) + t;
        if (s[k] < bs) { bs = s[k]; bj = j; }
    }
    unsigned long long bk =
        ((unsigned long long)__float_as_uint(bs) << 32) | (unsigned)bj;

    __shared__ unsigned long long cand[64];        // survivor keys (cap 64)
    __shared__ unsigned long long wtop[4 * TOPK];  // per-wave top-12 minima
    __shared__ float Tsh;                          // threshold
    __shared__ int   cnt[4];                       // per-wave survivor counts

    // Phase A: each wave sorts its 64 lane-minima once; keep its top-12.
    {
        unsigned long long key = bitonic64(bk, lane);
        if (lane < TOPK) wtop[w * TOPK + lane] = key;
    }
    __syncthreads();

    // Phase B: wave 0 sorts the 48 candidates -> exact 12th-smallest minimum T.
    if (w == 0) {
        unsigned long long k2 = (lane < 4 * TOPK) ? wtop[lane] : ~0ULL;
        k2 = bitonic64(k2, lane);
        if (lane == TOPK - 1) Tsh = __uint_as_float((unsigned)(k2 >> 32));
    }
    __syncthreads();
    const float T = Tsh;

    // Phase C: filter register-resident values against T, count + prefix.
    int c = 0;
    #pragma unroll
    for (int k = 0; k < 16; ++k) c += (s[k] <= T) ? 1 : 0;

    int pfx = c;                                   // inclusive scan over wave
    #pragma unroll
    for (int off = 1; off < 64; off <<= 1) {
        int o = __shfl_up(pfx, off, 64);
        if (lane >= off) pfx += o;
    }
    if (lane == 63) cnt[w] = pfx;
    __syncthreads();

    const int total = cnt[0] + cnt[1] + cnt[2] + cnt[3];   // block-uniform

    if (total <= 64) {
        int base = 0;
        for (int ww = 0; ww < w; ++ww) base += cnt[ww];
        int o = base + (pfx - c);                  // exclusive offset
        #pragma unroll
        for (int k = 0; k < 16; ++k) {
            if (s[k] <= T)
                cand[o++] = ((unsigned long long)__float_as_uint(s[k]) << 32)
                            | (unsigned)((k << 8) + t);
        }
        __syncthreads();

        if (w == 0) {
            unsigned long long k3 = (lane < total) ? cand[lane] : ~0ULL;
            k3 = bitonic64(k3, lane);              // total >= 12 guaranteed
            if (lane < TOPK) {
                int   j  = (int)(k3 & 0xffffffffULL);
                float ss = __uint_as_float((unsigned)(k3 >> 32));
                float d  = sqrtf(ss + 2.0e-4f);    // sqrt(sum(x[:2]^2 + 1e-4))
                float m  = (d <= 1.0f) ? 1.0f : 0.0f;
                int p = i * TOPK + lane;
                out[OFF_MASK + p]        = m;
                out[OFF_IDX + 2 * p]     = (float)i;
                out[OFF_IDX + 2 * p + 1] = (float)j;
            }
        }
        return;                                    // uniform exit
    }

    // -----------------------------------------------------------------------
    // Fallback (pathological ties only): original wave-local 12-pop + merge.
    // s[] and bk are untouched by the filter phase.
    // -----------------------------------------------------------------------
    unsigned long long mykey = ~0ULL;
    for (int it = 0; it < TOPK; ++it) {
        unsigned long long vk = bk;
        #pragma unroll
        for (int off = 1; off < 64; off <<= 1) {
            unsigned long long ok = __shfl_xor(vk, off, 64);
            vk = (ok < vk) ? ok : vk;
        }
        if (lane == it) mykey = vk;                // record pop #it
        int wj = (int)(vk & 0xffffffffULL);        // winning j (this wave's range)
        if ((wj & 63) == lane) {                   // I own it: pop + recompute
            int kk = wj >> 8;
            #pragma unroll
            for (int k = 0; k < 16; ++k)
                if (k == kk) s[k] = 3.0e38f;
            float nbs = s[0]; int nbj = t;
            #pragma unroll
            for (int k = 1; k < 16; ++k) {
                int j = (k << 8) + t;
                if (s[k] < nbs) { nbs = s[k]; nbj = j; }
            }
            bk = ((unsigned long long)__float_as_uint(nbs) << 32) | (unsigned)nbj;
        }
    }
    if (lane < TOPK) cand[w * TOPK + lane] = mykey;
    __syncthreads();

    if (w == 0) {
        unsigned long long k3 = (lane < 4 * TOPK) ? cand[lane] : ~0ULL;
        k3 = bitonic64(k3, lane);
        if (lane < TOPK) {
            int   j  = (int)(k3 & 0xffffffffULL);
            float ss = __uint_as_float((unsigned)(k3 >> 32));
            float d  = sqrtf(ss + 2.0e-4f);
            float m  = (d <= 1.0f) ? 1.0f : 0.0f;
            int p = i * TOPK + lane;
            out[OFF_MASK + p]        = m;
            out[OFF_IDX + 2 * p]     = (float)i;
            out[OFF_IDX + 2 * p + 1] = (float)j;
        }
    }
}

// ---------------------------------------------------------------------------
// K2: per-neighbor MLP 6->64->128->64->1.
// Block = 512 threads = 8 waves handling 64 pairs: lane (t&63) = pair,
// wave chunk ch = readfirstlane(t>>6) -> SGPR, so ALL weight/bias addresses
// are compiler-provably scalar => s_load + v_fmac_f32(v,s,v), zero VMEM in
// the inner loops. Activations pass via LDS [neuron][pair] (lane=pair ->
// conflict-free). 50 KB LDS -> 3 blocks/CU, 24 waves/CU.
// ---------------------------------------------------------------------------
__global__ __launch_bounds__(512, 6) void mlp_block(
        const float* __restrict__ x, const float* __restrict__ rp,
        const float* __restrict__ W1, const float* __restrict__ b1,
        const float* __restrict__ W2, const float* __restrict__ b2,
        const float* __restrict__ W3, const float* __restrict__ b3,
        const float* __restrict__ W4, const float* __restrict__ b4,
        float* out) {
    __shared__ float h1s[64 * 64];    // [m][pair] 16 KB
    __shared__ float h2s[128 * 64];   // [j][pair] 32 KB
    __shared__ float p4s[8 * 64];     // [chunk][pair] 2 KB

    const int t  = threadIdx.x;
    const int pl = t & 63;                                   // pair lane (vector)
    const int ch = __builtin_amdgcn_readfirstlane(t >> 6);   // chunk (SGPR!)
    const int p  = blockIdx.x * 64 + pl;
    const int i  = p / TOPK;
    const int j  = (int)out[OFF_IDX + 2 * p + 1];   // written by topk_rows

    const float4 v = ((const float4*)x)[(size_t)i * NN + j];
    const float d  = sqrtf(v.x * v.x + v.y * v.y + 2.0e-4f);
    float xin[6];
    xin[0] = v.x; xin[1] = v.y; xin[2] = v.z; xin[3] = v.w;
    xin[4] = (i == j) ? 1.0f : 0.0f;
    xin[5] = d - rp[0];

    // Phase 1: h1 neurons [ch*8, ch*8+8)   (weights via s_load)
    #pragma unroll
    for (int q = 0; q < 8; ++q) {
        int m = ch * 8 + q;
        const float* w = W1 + m * 6;
        float a = b1[m];
        #pragma unroll
        for (int c = 0; c < 6; ++c) a += w[c] * xin[c];
        h1s[m * 64 + pl] = fmaxf(a, 0.0f);
    }
    __syncthreads();

    // Phase 2: h2 neurons [ch*16, ch*16+16), k streamed in parts of 16
    float acc[16];
    #pragma unroll
    for (int q = 0; q < 16; ++q) acc[q] = b2[ch * 16 + q];
    for (int part = 0; part < 4; ++part) {
        float h1r[16];
        #pragma unroll
        for (int k = 0; k < 16; ++k) h1r[k] = h1s[(part * 16 + k) * 64 + pl];
        #pragma unroll
        for (int q = 0; q < 16; ++q) {
            const float* w = W2 + (ch * 16 + q) * 64 + part * 16;  // scalar addr
            #pragma unroll
            for (int k = 0; k < 16; ++k) acc[q] += w[k] * h1r[k];
        }
    }
    #pragma unroll
    for (int q = 0; q < 16; ++q) h2s[(ch * 16 + q) * 64 + pl] = fmaxf(acc[q], 0.0f);
    __syncthreads();

    // Phase 3: h3 neurons [ch*8, ch*8+8), j streamed in parts of 16
    float h3[8];
    #pragma unroll
    for (int q = 0; q < 8; ++q) h3[q] = b3[ch * 8 + q];
    for (int part = 0; part < 8; ++part) {
        float h2r[16];
        #pragma unroll
        for (int k = 0; k < 16; ++k) h2r[k] = h2s[(part * 16 + k) * 64 + pl];
        #pragma unroll
        for (int q = 0; q < 8; ++q) {
            const float* w = W3 + (ch * 8 + q) * 128 + part * 16;  // scalar addr
            #pragma unroll
            for (int k = 0; k < 16; ++k) h3[q] += w[k] * h2r[k];
        }
    }
    // Layer 4 partial over my 8 h3 outputs
    float partial = 0.0f;
    #pragma unroll
    for (int q = 0; q < 8; ++q) partial += W4[ch * 8 + q] * fmaxf(h3[q], 0.0f);
    p4s[ch * 64 + pl] = partial;
    __syncthreads();

    // Phase 4: reduce the 8 chunk-partials per pair, apply bias + mask
    if (t < 64) {
        float s = b4[0];
        #pragma unroll
        for (int c = 0; c < 8; ++c) s += p4s[c * 64 + t];
        int pp = blockIdx.x * 64 + t;
        out[pp] = s * out[OFF_MASK + pp];
    }
}

// ---------------------------------------------------------------------------
extern "C" void kernel_launch(void* const* d_in, const int* in_sizes, int n_in,
                              void* d_out, int out_size, void* d_ws, size_t ws_size,
                              hipStream_t stream) {
    const float* x  = (const float*)d_in[0];
    const float* rp = (const float*)d_in[1];
    const float* W1 = (const float*)d_in[2];
    const float* b1 = (const float*)d_in[3];
    const float* W2 = (const float*)d_in[4];
    const float* b2 = (const float*)d_in[5];
    const float* W3 = (const float*)d_in[6];
    const float* b3 = (const float*)d_in[7];
    const float* W4 = (const float*)d_in[8];
    const float* b4 = (const float*)d_in[9];
    float* out = (float*)d_out;

    topk_rows<<<NN, 256, 0, stream>>>(x, out);
    mlp_block<<<NP / 64, 512, 0, stream>>>(x, rp, W1, b1, W2, b2, W3, b3, W4, b4, out);
}